// Round 5
// baseline (344.275 us; speedup 1.0000x reference)
//
#include <hip/hip_runtime.h>

#define F 128

typedef __bf16 bf16x8 __attribute__((ext_vector_type(8)));
typedef float f32x4 __attribute__((ext_vector_type(4)));

// ---------------- setup kernels ----------------

__global__ __launch_bounds__(256) void k_init(float* deg, float* gacc, int N, int G) {
    int i = blockIdx.x * 256 + threadIdx.x;
    if (i < N) deg[i] = 1.0f;               // self-loop
    if (i < G) gacc[i] = 0.0f;
}

// degree count only: random-address atomics, low contention
__global__ __launch_bounds__(256) void k_count(const int* __restrict__ dst, float* deg, int E) {
    int i = blockIdx.x * 256 + threadIdx.x;
    if (i < E) unsafeAtomicAdd(&deg[dst[i]], 1.0f);
}

// graph node counts via binary search (batch is sorted) — no atomics
__global__ __launch_bounds__(256) void k_cnt(const int* __restrict__ batch, float* __restrict__ cnt,
                                             int N, int G) {
    int g = blockIdx.x * 256 + threadIdx.x;
    if (g >= G) return;
    int lo0 = 0, hi = N;
    while (lo0 < hi) { int mid = (lo0 + hi) >> 1; if (batch[mid] < g) lo0 = mid + 1; else hi = mid; }
    int lo1 = lo0; hi = N;
    while (lo1 < hi) { int mid = (lo1 + hi) >> 1; if (batch[mid] < g + 1) lo1 = mid + 1; else hi = mid; }
    cnt[g] = (float)(lo1 - lo0);
}

// exclusive scan of (deg[i]-1) = real in-degree, 1024 elems/block; also computes dis = rsqrt(deg)
__global__ __launch_bounds__(256) void k_scan1(const float* __restrict__ deg, int* __restrict__ pref,
                                               int* __restrict__ bsum, float* __restrict__ dis, int N) {
    int t = threadIdx.x;
    int base = blockIdx.x * 1024 + t * 4;
    int v[4]; int s = 0;
#pragma unroll
    for (int j = 0; j < 4; ++j) {
        int idx = base + j;
        float dv = (idx < N) ? deg[idx] : 1.0f;
        if (idx < N) dis[idx] = rsqrtf(dv);
        v[j] = (idx < N) ? ((int)dv - 1) : 0; s += v[j];
    }
    int lane = t & 63, w = t >> 6;
    int inc = s;
#pragma unroll
    for (int d = 1; d < 64; d <<= 1) { int o = __shfl_up(inc, d); if (lane >= d) inc += o; }
    __shared__ int wtot[4];
    if (lane == 63) wtot[w] = inc;
    __syncthreads();
    int woff = 0;
#pragma unroll
    for (int i = 0; i < 4; ++i) if (i < w) woff += wtot[i];
    int run = woff + inc - s;               // exclusive prefix of this thread's chunk
#pragma unroll
    for (int j = 0; j < 4; ++j) { int idx = base + j; if (idx < N) pref[idx] = run; run += v[j]; }
    if (t == 255) bsum[blockIdx.x] = woff + inc;
}

__global__ void k_scan2(int* bsum, int B) {
    if (threadIdx.x == 0) { int run = 0; for (int i = 0; i < B; ++i) { int x = bsum[i]; bsum[i] = run; run += x; } }
}

__global__ __launch_bounds__(256) void k_scan3(int* __restrict__ pref, const int* __restrict__ bsum,
                                               int* __restrict__ cursor, int N, int E) {
    int i = blockIdx.x * 256 + threadIdx.x;
    if (i < N) {
        int v = pref[i] + bsum[i >> 10];
        pref[i] = v;
        cursor[i] = v;
    }
    if (i == 0) pref[N] = E;
}

// CSR fill: only src indices (edge weights are algebraically eliminated)
__global__ __launch_bounds__(256) void k_fill(const int* __restrict__ src, const int* __restrict__ dst,
                                              int* __restrict__ cursor, int* __restrict__ srcs, int E) {
    int e = blockIdx.x * 256 + threadIdx.x;
    if (e < E) {
        int s = src[e], d = dst[e];
        int slot = atomicAdd(&cursor[d], 1);
        srcs[slot] = s;
    }
}

// w2l = W2 @ Wlin  (128x1); cconst = b2 . Wlin + blin
__global__ __launch_bounds__(128) void k_w2l(const float* __restrict__ W2, const float* __restrict__ Wlin,
                                             const float* __restrict__ b2, const float* __restrict__ blin,
                                             float* __restrict__ w2l, float* __restrict__ cconst) {
    int k = threadIdx.x;
    float s = 0.0f;
    for (int j = 0; j < F; j += 4) {
        float4 w = *(const float4*)&W2[k * F + j];
        float4 l = *(const float4*)&Wlin[j];
        s += w.x * l.x + w.y * l.y + w.z * l.z + w.w * l.w;
    }
    w2l[k] = s;
    __shared__ float sh[F];
    sh[k] = b2[k] * Wlin[k];
    __syncthreads();
    if (k == 0) {
        float c = blin[0];
        for (int j = 0; j < F; ++j) c += sh[j];
        *cconst = c;
    }
}

// W[k][n] fp32 -> WT[n][k] split bf16 (hi + residual lo)
__global__ __launch_bounds__(256) void k_wconv(const float* __restrict__ W,
                                               __bf16* __restrict__ WTh, __bf16* __restrict__ WTl) {
    int idx = blockIdx.x * 256 + threadIdx.x;     // 16384 elements
    int k = idx >> 7, n = idx & 127;
    float w = W[idx];
    __bf16 h = (__bf16)w;
    WTh[n * F + k] = h;
    WTl[n * F + k] = (__bf16)(w - (float)h);
}

// ---------------- MFMA GEMM: Y[n] = dis[n] * (X @ W)[n]  (row-scaled epilogue) ----------------
// split-bf16 (hi+lo), 3 MFMA products: hh + lh + hl  (ll ~2^-18, dropped).
// 16 rows/wave, 64 rows/block -> 6250 waves (24/CU). B-frag + A-tile software prefetch.
__global__ __launch_bounds__(256) void k_gemm_mfma(const float* __restrict__ X,
                                                   const __bf16* __restrict__ WTh,
                                                   const __bf16* __restrict__ WTl,
                                                   const float* __restrict__ dis,
                                                   float* __restrict__ Y, int N) {
    int lane = threadIdx.x & 63, wave = threadIdx.x >> 6;
    int quad = lane >> 4, m = lane & 15;
    int r0 = blockIdx.x * 64 + wave * 16;

    f32x4 acc[8];
#pragma unroll
    for (int c = 0; c < 8; ++c) acc[c] = (f32x4)0.0f;

    int ra = r0 + m; if (ra >= N) ra = N - 1;       // clamp: duplicate read, store guarded
    const float* px = &X[(size_t)ra * F + quad * 8];

    // preload A (t=0) and B (t=0,c=0)
    float4 a0 = *(const float4*)px;
    float4 a1 = *(const float4*)(px + 4);
    size_t b00 = (size_t)(0 * 16 + m) * F + quad * 8;
    bf16x8 bh = *(const bf16x8*)(WTh + b00);
    bf16x8 bl = *(const bf16x8*)(WTl + b00);

#pragma unroll 1
    for (int t = 0; t < 4; ++t) {
        // convert A to split bf16
        float fa[8] = {a0.x, a0.y, a0.z, a0.w, a1.x, a1.y, a1.z, a1.w};
        bf16x8 ah, al;
#pragma unroll
        for (int j = 0; j < 8; ++j) {
            __bf16 h = (__bf16)fa[j]; ah[j] = h; al[j] = (__bf16)(fa[j] - (float)h);
        }
        // prefetch next A tile
        if (t < 3) {
            a0 = *(const float4*)(px + (t + 1) * 32);
            a1 = *(const float4*)(px + (t + 1) * 32 + 4);
        }
#pragma unroll
        for (int c = 0; c < 8; ++c) {
            bf16x8 cbh = bh, cbl = bl;
            // prefetch next B fragments (next c, or c=0 of next t)
            int nt = (c < 7) ? t : t + 1;
            int nc = (c < 7) ? c + 1 : 0;
            if (nt < 4) {
                size_t bo = (size_t)(nc * 16 + m) * F + nt * 32 + quad * 8;
                bh = *(const bf16x8*)(WTh + bo);
                bl = *(const bf16x8*)(WTl + bo);
            }
            acc[c] = __builtin_amdgcn_mfma_f32_16x16x32_bf16(ah, cbh, acc[c], 0, 0, 0);
            acc[c] = __builtin_amdgcn_mfma_f32_16x16x32_bf16(al, cbh, acc[c], 0, 0, 0);
            acc[c] = __builtin_amdgcn_mfma_f32_16x16x32_bf16(ah, cbl, acc[c], 0, 0, 0);
        }
    }

    // C/D layout: col = lane&15 (=m), row = quad*4 + reg; scale row by dis[row]
    int rbase = r0 + quad * 4;
#pragma unroll
    for (int r = 0; r < 4; ++r) {
        int row = rbase + r;
        if (row < N) {
            float dr = dis[row];
#pragma unroll
            for (int c = 0; c < 8; ++c)
                Y[(size_t)row * F + c * 16 + m] = acc[c][r] * dr;
        }
    }
}

// ---------------- layer-1 aggregation fused with zt = dis * (relu(b1 + dis*sum) . w2l) ------
// hWs is pre-scaled by dis (GEMM epilogue) -> edge loop is PURE ADDS, no weights.
__global__ __launch_bounds__(256) void k_agg_z(const float* __restrict__ hWs, const float* __restrict__ dis,
                                               const int* __restrict__ rowptr, const int* __restrict__ srcs,
                                               const float* __restrict__ bias, const float* __restrict__ w2l,
                                               float* __restrict__ zt, int N) {
    int node = blockIdx.x * 8 + (threadIdx.x >> 5);
    if (node >= N) return;
    int lane = threadIdx.x & 31;
    float di = dis[node];
    float4 sum = *(const float4*)&hWs[(size_t)node * F + lane * 4];  // self term (dis*hW)
    int e0 = rowptr[node], e1 = rowptr[node + 1];
    int e = e0;
    for (; e + 4 <= e1; e += 4) {
        int s0 = srcs[e], s1 = srcs[e + 1], s2 = srcs[e + 2], s3 = srcs[e + 3];
        float4 v0 = *(const float4*)&hWs[(size_t)s0 * F + lane * 4];
        float4 v1 = *(const float4*)&hWs[(size_t)s1 * F + lane * 4];
        float4 v2 = *(const float4*)&hWs[(size_t)s2 * F + lane * 4];
        float4 v3 = *(const float4*)&hWs[(size_t)s3 * F + lane * 4];
        sum.x += v0.x + v1.x + v2.x + v3.x;
        sum.y += v0.y + v1.y + v2.y + v3.y;
        sum.z += v0.z + v1.z + v2.z + v3.z;
        sum.w += v0.w + v1.w + v2.w + v3.w;
    }
    for (; e < e1; ++e) {
        int s = srcs[e];
        float4 v = *(const float4*)&hWs[(size_t)s * F + lane * 4];
        sum.x += v.x; sum.y += v.y; sum.z += v.z; sum.w += v.w;
    }
    float4 b = *(const float4*)&bias[lane * 4];
    float4 h;
    h.x = fmaxf(fmaf(di, sum.x, b.x), 0.0f);
    h.y = fmaxf(fmaf(di, sum.y, b.y), 0.0f);
    h.z = fmaxf(fmaf(di, sum.z, b.z), 0.0f);
    h.w = fmaxf(fmaf(di, sum.w, b.w), 0.0f);
    float4 w = *(const float4*)&w2l[lane * 4];
    float p = h.x * w.x + h.y * w.y + h.z * w.z + h.w * w.w;
#pragma unroll
    for (int d = 1; d < 32; d <<= 1) p += __shfl_xor(p, d);
    if (lane == 0) zt[node] = di * p;
}

// ---------------- layer-2 scalar aggregation + mean-pool ----------------
// y[n] = dis[n] * (zt[n] + sum_s zt[s]); gacc[batch[n]] += y[n]
__global__ __launch_bounds__(256) void k_pool_z(const float* __restrict__ zt, const float* __restrict__ dis,
                                                const int* __restrict__ rowptr, const int* __restrict__ srcs,
                                                const int* __restrict__ batch,
                                                float* __restrict__ gacc, int N) {
    int n = blockIdx.x * 256 + threadIdx.x;
    float y = 0.0f;
    int b = -1;
    if (n < N) {
        float s = zt[n];
        int e0 = rowptr[n], e1 = rowptr[n + 1];
        int e = e0;
        for (; e + 4 <= e1; e += 4) {
            int s0 = srcs[e], s1 = srcs[e + 1], s2 = srcs[e + 2], s3 = srcs[e + 3];
            s += zt[s0] + zt[s1] + zt[s2] + zt[s3];
        }
        for (; e < e1; ++e) s += zt[srcs[e]];
        y = dis[n] * s;
        b = batch[n];
    }
    // batch is sorted -> if wave endpoints agree, whole wave is one graph
    int bfirst = __shfl(b, 0), blast = __shfl(b, 63);
    if (bfirst == blast && bfirst >= 0) {
#pragma unroll
        for (int d = 1; d < 64; d <<= 1) y += __shfl_xor(y, d);
        if ((threadIdx.x & 63) == 0) unsafeAtomicAdd(&gacc[bfirst], y);
    } else if (n < N) {
        unsafeAtomicAdd(&gacc[b], y);
    }
}

__global__ __launch_bounds__(256) void k_final(const float* __restrict__ gacc, const float* __restrict__ cnt,
                                               const float* __restrict__ cconst, float* __restrict__ out, int G) {
    int g = blockIdx.x * 256 + threadIdx.x;
    if (g < G) out[g] = gacc[g] / fmaxf(cnt[g], 1.0f) + cconst[0];
}

// ---------------- launch ----------------

extern "C" void kernel_launch(void* const* d_in, const int* in_sizes, int n_in,
                              void* d_out, int out_size, void* d_ws, size_t ws_size,
                              hipStream_t stream) {
    const float* x    = (const float*)d_in[0];
    const int*   ei   = (const int*)d_in[1];
    const int*   batch= (const int*)d_in[2];
    const float* W1   = (const float*)d_in[3];
    const float* b1   = (const float*)d_in[4];
    const float* W2   = (const float*)d_in[5];
    const float* b2   = (const float*)d_in[6];
    const float* Wlin = (const float*)d_in[7];
    const float* blin = (const float*)d_in[8];
    float* out = (float*)d_out;

    const int N = in_sizes[2];          // 100000
    const int E = in_sizes[1] / 2;      // 600000
    const int G = out_size;             // 512
    const int* src = ei;
    const int* dst = ei + E;

    // workspace carve-up (256B aligned)
    char* p = (char*)d_ws;
    auto take = [&](size_t bytes) { char* q = p; p += (bytes + 255) & ~(size_t)255; return q; };
    float*  bufA   = (float*)take((size_t)N * F * 4);   // hWs = dis * (x @ W1)
    float*  ztbuf  = (float*)take((size_t)N * 4);
    float*  deg    = (float*)take((size_t)N * 4);
    float*  dis    = (float*)take((size_t)N * 4);
    int*    rowptr = (int*)  take((size_t)(N + 1) * 4);
    int*    cursor = (int*)  take((size_t)N * 4);
    int*    srcs   = (int*)  take((size_t)E * 4);
    int*    bsum   = (int*)  take(4096);
    float*  cnt    = (float*)take((size_t)G * 4);
    float*  gacc   = (float*)take((size_t)G * 4);
    float*  w2l    = (float*)take((size_t)F * 4);
    float*  cconst = (float*)take(256);
    __bf16* WTh    = (__bf16*)take((size_t)F * F * 2);
    __bf16* WTl    = (__bf16*)take((size_t)F * F * 2);

    const int nbN = (N + 255) / 256;
    const int nbE = (E + 255) / 256;
    const int nbS = (N + 1023) / 1024;

    k_init <<<nbN, 256, 0, stream>>>(deg, gacc, N, G);
    k_count<<<nbE, 256, 0, stream>>>(dst, deg, E);
    k_cnt  <<<(G + 255) / 256, 256, 0, stream>>>(batch, cnt, N, G);
    k_scan1<<<nbS, 256, 0, stream>>>(deg, rowptr, bsum, dis, N);
    k_scan2<<<1, 64, 0, stream>>>(bsum, nbS);
    k_scan3<<<nbN, 256, 0, stream>>>(rowptr, bsum, cursor, N, E);
    k_fill <<<nbE, 256, 0, stream>>>(src, dst, cursor, srcs, E);
    k_w2l  <<<1, 128, 0, stream>>>(W2, Wlin, b2, blin, w2l, cconst);
    k_wconv<<<(F * F + 255) / 256, 256, 0, stream>>>(W1, WTh, WTl);

    // layer 1 GEMM (MFMA split-bf16), epilogue scales rows by dis: hWs
    k_gemm_mfma<<<(N + 63) / 64, 256, 0, stream>>>(x, WTh, WTl, dis, bufA, N);
    // fused: zt = dis * (relu(b1 + dis*sum(hWs)) . w2l)
    k_agg_z<<<(N + 7) / 8, 256, 0, stream>>>(bufA, dis, rowptr, srcs, b1, w2l, ztbuf, N);
    // layer-2 scalar aggregation + pooling
    k_pool_z<<<nbN, 256, 0, stream>>>(ztbuf, dis, rowptr, srcs, batch, gacc, N);

    k_final<<<(G + 255) / 256, 256, 0, stream>>>(gacc, cnt, cconst, out, G);
}

// Round 6
// 273.444 us; speedup vs baseline: 1.2590x; 1.2590x over previous
//
#include <hip/hip_runtime.h>

#define F 128

typedef __bf16 bf16x8 __attribute__((ext_vector_type(8)));
typedef float f32x4 __attribute__((ext_vector_type(4)));

// ---------------- setup kernels ----------------

__global__ __launch_bounds__(256) void k_init(float* deg, float* gacc, int N, int G) {
    int i = blockIdx.x * 256 + threadIdx.x;
    if (i < N) deg[i] = 1.0f;               // self-loop
    if (i < G) gacc[i] = 0.0f;
}

// degree count only: random-address atomics, low contention
__global__ __launch_bounds__(256) void k_count(const int* __restrict__ dst, float* deg, int E) {
    int i = blockIdx.x * 256 + threadIdx.x;
    if (i < E) unsafeAtomicAdd(&deg[dst[i]], 1.0f);
}

// graph node counts via binary search (batch is sorted) — no atomics
__global__ __launch_bounds__(256) void k_cnt(const int* __restrict__ batch, float* __restrict__ cnt,
                                             int N, int G) {
    int g = blockIdx.x * 256 + threadIdx.x;
    if (g >= G) return;
    int lo0 = 0, hi = N;
    while (lo0 < hi) { int mid = (lo0 + hi) >> 1; if (batch[mid] < g) lo0 = mid + 1; else hi = mid; }
    int lo1 = lo0; hi = N;
    while (lo1 < hi) { int mid = (lo1 + hi) >> 1; if (batch[mid] < g + 1) lo1 = mid + 1; else hi = mid; }
    cnt[g] = (float)(lo1 - lo0);
}

// exclusive scan of (deg[i]-1) = real in-degree, 1024 elems/block; also computes dis = rsqrt(deg)
__global__ __launch_bounds__(256) void k_scan1(const float* __restrict__ deg, int* __restrict__ pref,
                                               int* __restrict__ bsum, float* __restrict__ dis, int N) {
    int t = threadIdx.x;
    int base = blockIdx.x * 1024 + t * 4;
    int v[4]; int s = 0;
#pragma unroll
    for (int j = 0; j < 4; ++j) {
        int idx = base + j;
        float dv = (idx < N) ? deg[idx] : 1.0f;
        if (idx < N) dis[idx] = rsqrtf(dv);
        v[j] = (idx < N) ? ((int)dv - 1) : 0; s += v[j];
    }
    int lane = t & 63, w = t >> 6;
    int inc = s;
#pragma unroll
    for (int d = 1; d < 64; d <<= 1) { int o = __shfl_up(inc, d); if (lane >= d) inc += o; }
    __shared__ int wtot[4];
    if (lane == 63) wtot[w] = inc;
    __syncthreads();
    int woff = 0;
#pragma unroll
    for (int i = 0; i < 4; ++i) if (i < w) woff += wtot[i];
    int run = woff + inc - s;               // exclusive prefix of this thread's chunk
#pragma unroll
    for (int j = 0; j < 4; ++j) { int idx = base + j; if (idx < N) pref[idx] = run; run += v[j]; }
    if (t == 255) bsum[blockIdx.x] = woff + inc;
}

__global__ void k_scan2(int* bsum, int B) {
    if (threadIdx.x == 0) { int run = 0; for (int i = 0; i < B; ++i) { int x = bsum[i]; bsum[i] = run; run += x; } }
}

__global__ __launch_bounds__(256) void k_scan3(int* __restrict__ pref, const int* __restrict__ bsum,
                                               int* __restrict__ cursor, int N, int E) {
    int i = blockIdx.x * 256 + threadIdx.x;
    if (i < N) {
        int v = pref[i] + bsum[i >> 10];
        pref[i] = v;
        cursor[i] = v;
    }
    if (i == 0) pref[N] = E;
}

// CSR fill: only src indices (edge weights are algebraically eliminated)
__global__ __launch_bounds__(256) void k_fill(const int* __restrict__ src, const int* __restrict__ dst,
                                              int* __restrict__ cursor, int* __restrict__ srcs, int E) {
    int e = blockIdx.x * 256 + threadIdx.x;
    if (e < E) {
        int s = src[e], d = dst[e];
        int slot = atomicAdd(&cursor[d], 1);
        srcs[slot] = s;
    }
}

// w2l = W2 @ Wlin  (128x1); cconst = b2 . Wlin + blin
__global__ __launch_bounds__(128) void k_w2l(const float* __restrict__ W2, const float* __restrict__ Wlin,
                                             const float* __restrict__ b2, const float* __restrict__ blin,
                                             float* __restrict__ w2l, float* __restrict__ cconst) {
    int k = threadIdx.x;
    float s = 0.0f;
    for (int j = 0; j < F; j += 4) {
        float4 w = *(const float4*)&W2[k * F + j];
        float4 l = *(const float4*)&Wlin[j];
        s += w.x * l.x + w.y * l.y + w.z * l.z + w.w * l.w;
    }
    w2l[k] = s;
    __shared__ float sh[F];
    sh[k] = b2[k] * Wlin[k];
    __syncthreads();
    if (k == 0) {
        float c = blin[0];
        for (int j = 0; j < F; ++j) c += sh[j];
        *cconst = c;
    }
}

// W[k][n] fp32 -> bf16 B-fragments in MFMA-fragment-linear order:
// Bswz[((t*8 + c)*64 + lane)*8 + j] = W[t*32 + (lane>>4)*8 + j][c*16 + (lane&15)]
// -> each (t,c) fragment load is one fully-coalesced 1KB wave transaction.
__global__ __launch_bounds__(256) void k_wconv(const float* __restrict__ W, __bf16* __restrict__ Bswz) {
    int o = blockIdx.x * 256 + threadIdx.x;       // 16384 elements
    int j = o & 7;
    int lane = (o >> 3) & 63;
    int tc = o >> 9;                              // 0..31
    int t = tc >> 3, c = tc & 7;
    int k = t * 32 + (lane >> 4) * 8 + j;
    int n = c * 16 + (lane & 15);
    Bswz[o] = (__bf16)W[k * F + n];
}

// ---------------- MFMA GEMM: Yb[n] = bf16( dis[n] * (X @ W)[n] ) ----------------
// x split hi+lo (2 MFMA products), W single bf16 (pre-swizzled, coalesced batched loads).
// 32 rows/wave (2 M-tiles), 128 rows/block -> 782 blocks, 3125 waves (12/CU).
__global__ __launch_bounds__(256) void k_gemm_mfma(const float* __restrict__ X,
                                                   const __bf16* __restrict__ Bswz,
                                                   const float* __restrict__ dis,
                                                   __bf16* __restrict__ Yb, int N) {
    int lane = threadIdx.x & 63, wave = threadIdx.x >> 6;
    int quad = lane >> 4, m = lane & 15;
    int r0 = blockIdx.x * 128 + wave * 32;

    f32x4 acc[2][8];
#pragma unroll
    for (int rt = 0; rt < 2; ++rt)
#pragma unroll
        for (int c = 0; c < 8; ++c) acc[rt][c] = (f32x4)0.0f;

    int ra = r0 + m;      if (ra >= N) ra = N - 1;   // clamp: duplicate read, store guarded
    int rb = r0 + 16 + m; if (rb >= N) rb = N - 1;
    const float* pxa = &X[(size_t)ra * F + quad * 8];
    const float* pxb = &X[(size_t)rb * F + quad * 8];

    // preload A for t=0
    float4 a0 = *(const float4*)pxa, a1 = *(const float4*)(pxa + 4);
    float4 a2 = *(const float4*)pxb, a3 = *(const float4*)(pxb + 4);

#pragma unroll 1
    for (int t = 0; t < 4; ++t) {
        // batched coalesced B loads: 8 independent 16B/lane loads, all issued before use
        const __bf16* bp = Bswz + (size_t)t * 4096 + lane * 8;
        bf16x8 B[8];
#pragma unroll
        for (int c = 0; c < 8; ++c) B[c] = *(const bf16x8*)(bp + c * 512);

        // convert A to split bf16
        float fa[8] = {a0.x, a0.y, a0.z, a0.w, a1.x, a1.y, a1.z, a1.w};
        float fb[8] = {a2.x, a2.y, a2.z, a2.w, a3.x, a3.y, a3.z, a3.w};
        bf16x8 ah0, al0, ah1, al1;
#pragma unroll
        for (int j = 0; j < 8; ++j) {
            __bf16 h0 = (__bf16)fa[j]; ah0[j] = h0; al0[j] = (__bf16)(fa[j] - (float)h0);
            __bf16 h1 = (__bf16)fb[j]; ah1[j] = h1; al1[j] = (__bf16)(fb[j] - (float)h1);
        }
        // prefetch next A tile
        if (t < 3) {
            a0 = *(const float4*)(pxa + (t + 1) * 32);
            a1 = *(const float4*)(pxa + (t + 1) * 32 + 4);
            a2 = *(const float4*)(pxb + (t + 1) * 32);
            a3 = *(const float4*)(pxb + (t + 1) * 32 + 4);
        }
#pragma unroll
        for (int c = 0; c < 8; ++c) {
            acc[0][c] = __builtin_amdgcn_mfma_f32_16x16x32_bf16(ah0, B[c], acc[0][c], 0, 0, 0);
            acc[0][c] = __builtin_amdgcn_mfma_f32_16x16x32_bf16(al0, B[c], acc[0][c], 0, 0, 0);
            acc[1][c] = __builtin_amdgcn_mfma_f32_16x16x32_bf16(ah1, B[c], acc[1][c], 0, 0, 0);
            acc[1][c] = __builtin_amdgcn_mfma_f32_16x16x32_bf16(al1, B[c], acc[1][c], 0, 0, 0);
        }
    }

    // C/D layout: col = c*16 + m, row = rt*16 + quad*4 + reg; scale by dis[row], store bf16
#pragma unroll
    for (int rt = 0; rt < 2; ++rt) {
        int rbase = r0 + rt * 16 + quad * 4;
#pragma unroll
        for (int r = 0; r < 4; ++r) {
            int row = rbase + r;
            if (row < N) {
                float dr = dis[row];
#pragma unroll
                for (int c = 0; c < 8; ++c)
                    Yb[(size_t)row * F + c * 16 + m] = (__bf16)(acc[rt][c][r] * dr);
            }
        }
    }
}

// ---------------- layer-1 aggregation fused with zt = dis * (relu(b1 + dis*sum) . w2l) ------
// hWb is bf16, pre-scaled by dis -> edge loop is pure adds. 16 lanes/node, 4 nodes/wave.
__global__ __launch_bounds__(256) void k_agg_z(const __bf16* __restrict__ hWb, const float* __restrict__ dis,
                                               const int* __restrict__ rowptr, const int* __restrict__ srcs,
                                               const float* __restrict__ bias, const float* __restrict__ w2l,
                                               float* __restrict__ zt, int N) {
    int node = blockIdx.x * 16 + (threadIdx.x >> 4);
    if (node >= N) return;
    int lane = threadIdx.x & 15;
    float di = dis[node];
    float s[8];
    {
        bf16x8 v = *(const bf16x8*)&hWb[(size_t)node * F + lane * 8];   // self term
#pragma unroll
        for (int j = 0; j < 8; ++j) s[j] = (float)v[j];
    }
    int e0 = rowptr[node], e1 = rowptr[node + 1];
    int e = e0;
    for (; e + 4 <= e1; e += 4) {
        int s0 = srcs[e], s1 = srcs[e + 1], s2 = srcs[e + 2], s3 = srcs[e + 3];
        bf16x8 v0 = *(const bf16x8*)&hWb[(size_t)s0 * F + lane * 8];
        bf16x8 v1 = *(const bf16x8*)&hWb[(size_t)s1 * F + lane * 8];
        bf16x8 v2 = *(const bf16x8*)&hWb[(size_t)s2 * F + lane * 8];
        bf16x8 v3 = *(const bf16x8*)&hWb[(size_t)s3 * F + lane * 8];
#pragma unroll
        for (int j = 0; j < 8; ++j)
            s[j] += (float)v0[j] + (float)v1[j] + (float)v2[j] + (float)v3[j];
    }
    for (; e < e1; ++e) {
        bf16x8 v = *(const bf16x8*)&hWb[(size_t)srcs[e] * F + lane * 8];
#pragma unroll
        for (int j = 0; j < 8; ++j) s[j] += (float)v[j];
    }
    float4 b0 = *(const float4*)&bias[lane * 8];
    float4 b1v = *(const float4*)&bias[lane * 8 + 4];
    float4 w0 = *(const float4*)&w2l[lane * 8];
    float4 w1v = *(const float4*)&w2l[lane * 8 + 4];
    float bb[8] = {b0.x, b0.y, b0.z, b0.w, b1v.x, b1v.y, b1v.z, b1v.w};
    float ww[8] = {w0.x, w0.y, w0.z, w0.w, w1v.x, w1v.y, w1v.z, w1v.w};
    float p = 0.0f;
#pragma unroll
    for (int j = 0; j < 8; ++j)
        p += fmaxf(fmaf(di, s[j], bb[j]), 0.0f) * ww[j];
#pragma unroll
    for (int d = 1; d < 16; d <<= 1) p += __shfl_xor(p, d);
    if (lane == 0) zt[node] = di * p;
}

// ---------------- layer-2 scalar aggregation + mean-pool ----------------
// y[n] = dis[n] * (zt[n] + sum_s zt[s]); gacc[batch[n]] += y[n]
__global__ __launch_bounds__(256) void k_pool_z(const float* __restrict__ zt, const float* __restrict__ dis,
                                                const int* __restrict__ rowptr, const int* __restrict__ srcs,
                                                const int* __restrict__ batch,
                                                float* __restrict__ gacc, int N) {
    int n = blockIdx.x * 256 + threadIdx.x;
    float y = 0.0f;
    int b = -1;
    if (n < N) {
        float s = zt[n];
        int e0 = rowptr[n], e1 = rowptr[n + 1];
        int e = e0;
        for (; e + 4 <= e1; e += 4) {
            int s0 = srcs[e], s1 = srcs[e + 1], s2 = srcs[e + 2], s3 = srcs[e + 3];
            s += zt[s0] + zt[s1] + zt[s2] + zt[s3];
        }
        for (; e < e1; ++e) s += zt[srcs[e]];
        y = dis[n] * s;
        b = batch[n];
    }
    // batch is sorted -> if wave endpoints agree, whole wave is one graph
    int bfirst = __shfl(b, 0), blast = __shfl(b, 63);
    if (bfirst == blast && bfirst >= 0) {
#pragma unroll
        for (int d = 1; d < 64; d <<= 1) y += __shfl_xor(y, d);
        if ((threadIdx.x & 63) == 0) unsafeAtomicAdd(&gacc[bfirst], y);
    } else if (n < N) {
        unsafeAtomicAdd(&gacc[b], y);
    }
}

__global__ __launch_bounds__(256) void k_final(const float* __restrict__ gacc, const float* __restrict__ cnt,
                                               const float* __restrict__ cconst, float* __restrict__ out, int G) {
    int g = blockIdx.x * 256 + threadIdx.x;
    if (g < G) out[g] = gacc[g] / fmaxf(cnt[g], 1.0f) + cconst[0];
}

// ---------------- launch ----------------

extern "C" void kernel_launch(void* const* d_in, const int* in_sizes, int n_in,
                              void* d_out, int out_size, void* d_ws, size_t ws_size,
                              hipStream_t stream) {
    const float* x    = (const float*)d_in[0];
    const int*   ei   = (const int*)d_in[1];
    const int*   batch= (const int*)d_in[2];
    const float* W1   = (const float*)d_in[3];
    const float* b1   = (const float*)d_in[4];
    const float* W2   = (const float*)d_in[5];
    const float* b2   = (const float*)d_in[6];
    const float* Wlin = (const float*)d_in[7];
    const float* blin = (const float*)d_in[8];
    float* out = (float*)d_out;

    const int N = in_sizes[2];          // 100000
    const int E = in_sizes[1] / 2;      // 600000
    const int G = out_size;             // 512
    const int* src = ei;
    const int* dst = ei + E;

    // workspace carve-up (256B aligned)
    char* p = (char*)d_ws;
    auto take = [&](size_t bytes) { char* q = p; p += (bytes + 255) & ~(size_t)255; return q; };
    __bf16* hWb    = (__bf16*)take((size_t)N * F * 2);  // bf16( dis * (x @ W1) )
    float*  ztbuf  = (float*)take((size_t)N * 4);
    float*  deg    = (float*)take((size_t)N * 4);
    float*  dis    = (float*)take((size_t)N * 4);
    int*    rowptr = (int*)  take((size_t)(N + 1) * 4);
    int*    cursor = (int*)  take((size_t)N * 4);
    int*    srcs   = (int*)  take((size_t)E * 4);
    int*    bsum   = (int*)  take(4096);
    float*  cnt    = (float*)take((size_t)G * 4);
    float*  gacc   = (float*)take((size_t)G * 4);
    float*  w2l    = (float*)take((size_t)F * 4);
    float*  cconst = (float*)take(256);
    __bf16* Bswz   = (__bf16*)take((size_t)F * F * 2);

    const int nbN = (N + 255) / 256;
    const int nbE = (E + 255) / 256;
    const int nbS = (N + 1023) / 1024;

    k_init <<<nbN, 256, 0, stream>>>(deg, gacc, N, G);
    k_count<<<nbE, 256, 0, stream>>>(dst, deg, E);
    k_cnt  <<<(G + 255) / 256, 256, 0, stream>>>(batch, cnt, N, G);
    k_scan1<<<nbS, 256, 0, stream>>>(deg, rowptr, bsum, dis, N);
    k_scan2<<<1, 64, 0, stream>>>(bsum, nbS);
    k_scan3<<<nbN, 256, 0, stream>>>(rowptr, bsum, cursor, N, E);
    k_fill <<<nbE, 256, 0, stream>>>(src, dst, cursor, srcs, E);
    k_w2l  <<<1, 128, 0, stream>>>(W2, Wlin, b2, blin, w2l, cconst);
    k_wconv<<<(F * F + 255) / 256, 256, 0, stream>>>(W1, Bswz);

    // layer 1 GEMM (MFMA, x-split bf16), epilogue scales rows by dis, stores bf16
    k_gemm_mfma<<<(N + 127) / 128, 256, 0, stream>>>(x, Bswz, dis, hWb, N);
    // fused: zt = dis * (relu(b1 + dis*sum(hWb)) . w2l)
    k_agg_z<<<(N + 15) / 16, 256, 0, stream>>>(hWb, dis, rowptr, srcs, b1, w2l, ztbuf, N);
    // layer-2 scalar aggregation + pooling
    k_pool_z<<<nbN, 256, 0, stream>>>(ztbuf, dis, rowptr, srcs, batch, gacc, N);

    k_final<<<(G + 255) / 256, 256, 0, stream>>>(gacc, cnt, cconst, out, G);
}

// Round 7
// 260.303 us; speedup vs baseline: 1.3226x; 1.0505x over previous
//
#include <hip/hip_runtime.h>

#define F 128

typedef __bf16 bf16x8 __attribute__((ext_vector_type(8)));
typedef float f32x4 __attribute__((ext_vector_type(4)));

// ---------------- setup kernels ----------------

__global__ __launch_bounds__(256) void k_init(float* deg, float* gacc, int N, int G) {
    int i = blockIdx.x * 256 + threadIdx.x;
    if (i < N) deg[i] = 1.0f;               // self-loop
    if (i < G) gacc[i] = 0.0f;
}

// degree count only: random-address atomics, low contention
__global__ __launch_bounds__(256) void k_count(const int* __restrict__ dst, float* deg, int E) {
    int i = blockIdx.x * 256 + threadIdx.x;
    if (i < E) unsafeAtomicAdd(&deg[dst[i]], 1.0f);
}

// fused prep: blocks 0..63 = W1 swizzle->bf16; block 64 = w2l+cconst; blocks 65.. = graph counts
__global__ __launch_bounds__(256) void k_prep(const float* __restrict__ W1, const float* __restrict__ W2,
                                              const float* __restrict__ Wlin, const float* __restrict__ b2,
                                              const float* __restrict__ blin, const int* __restrict__ batch,
                                              __bf16* __restrict__ Bswz, float* __restrict__ w2l,
                                              float* __restrict__ cconst, float* __restrict__ cnt,
                                              int N, int G) {
    int bid = blockIdx.x;
    if (bid < 64) {
        // Bswz[((t*8+c)*64+lane)*8+j] = W1[t*32+(lane>>4)*8+j][c*16+(lane&15)]
        int o = bid * 256 + threadIdx.x;              // 16384 elements
        int j = o & 7, lane = (o >> 3) & 63, tc = o >> 9;
        int t = tc >> 3, c = tc & 7;
        int k = t * 32 + (lane >> 4) * 8 + j;
        int n = c * 16 + (lane & 15);
        Bswz[o] = (__bf16)W1[k * F + n];
    } else if (bid == 64) {
        int k = threadIdx.x;
        __shared__ float sh[F];
        if (k < F) {
            float s = 0.0f;
            for (int j = 0; j < F; j += 4) {
                float4 w = *(const float4*)&W2[k * F + j];
                float4 l = *(const float4*)&Wlin[j];
                s += w.x * l.x + w.y * l.y + w.z * l.z + w.w * l.w;
            }
            w2l[k] = s;
            sh[k] = b2[k] * Wlin[k];
        }
        __syncthreads();
        if (k == 0) {
            float c = blin[0];
            for (int j = 0; j < F; ++j) c += sh[j];
            *cconst = c;
        }
    } else {
        int g = (bid - 65) * 256 + threadIdx.x;
        if (g < G) {
            int lo0 = 0, hi = N;
            while (lo0 < hi) { int mid = (lo0 + hi) >> 1; if (batch[mid] < g) lo0 = mid + 1; else hi = mid; }
            int lo1 = lo0; hi = N;
            while (lo1 < hi) { int mid = (lo1 + hi) >> 1; if (batch[mid] < g + 1) lo1 = mid + 1; else hi = mid; }
            cnt[g] = (float)(lo1 - lo0);
        }
    }
}

// exclusive scan of (deg[i]-1), 1024 elems/block; also dis = rsqrt(deg)
__global__ __launch_bounds__(256) void k_scan1(const float* __restrict__ deg, int* __restrict__ pref,
                                               int* __restrict__ bsum, float* __restrict__ dis, int N) {
    int t = threadIdx.x;
    int base = blockIdx.x * 1024 + t * 4;
    int v[4]; int s = 0;
#pragma unroll
    for (int j = 0; j < 4; ++j) {
        int idx = base + j;
        float dv = (idx < N) ? deg[idx] : 1.0f;
        if (idx < N) dis[idx] = rsqrtf(dv);
        v[j] = (idx < N) ? ((int)dv - 1) : 0; s += v[j];
    }
    int lane = t & 63, w = t >> 6;
    int inc = s;
#pragma unroll
    for (int d = 1; d < 64; d <<= 1) { int o = __shfl_up(inc, d); if (lane >= d) inc += o; }
    __shared__ int wtot[4];
    if (lane == 63) wtot[w] = inc;
    __syncthreads();
    int woff = 0;
#pragma unroll
    for (int i = 0; i < 4; ++i) if (i < w) woff += wtot[i];
    int run = woff + inc - s;
#pragma unroll
    for (int j = 0; j < 4; ++j) { int idx = base + j; if (idx < N) pref[idx] = run; run += v[j]; }
    if (t == 255) bsum[blockIdx.x] = woff + inc;
}

// global offset fused: block j needs sum of bsum[0 .. j>>2); reduce in-block (B <= ~400)
__global__ __launch_bounds__(256) void k_scan3(int* __restrict__ pref, const int* __restrict__ bsum,
                                               int* __restrict__ cursor, int N, int E) {
    int t = threadIdx.x;
    int chunk = blockIdx.x >> 2;                  // which scan1 block my indices belong to
    int partial = 0;
    for (int i = t; i < chunk; i += 256) partial += bsum[i];
    int lane = t & 63, w = t >> 6;
#pragma unroll
    for (int d = 1; d < 64; d <<= 1) partial += __shfl_xor(partial, d);
    __shared__ int ws4[4];
    if (lane == 0) ws4[w] = partial;
    __syncthreads();
    int off = ws4[0] + ws4[1] + ws4[2] + ws4[3];
    int i = blockIdx.x * 256 + t;
    if (i < N) {
        int v = pref[i] + off;
        pref[i] = v;
        cursor[i] = v;
    }
    if (i == 0) pref[N] = E;
}

// CSR fill: only src indices (edge weights algebraically eliminated)
__global__ __launch_bounds__(256) void k_fill(const int* __restrict__ src, const int* __restrict__ dst,
                                              int* __restrict__ cursor, int* __restrict__ srcs, int E) {
    int e = blockIdx.x * 256 + threadIdx.x;
    if (e < E) {
        int s = src[e], d = dst[e];
        int slot = atomicAdd(&cursor[d], 1);
        srcs[slot] = s;
    }
}

// ---------------- MFMA GEMM: Yb[n] = bf16( dis[n] * (X @ W)[n] ) ----------------
__global__ __launch_bounds__(256) void k_gemm_mfma(const float* __restrict__ X,
                                                   const __bf16* __restrict__ Bswz,
                                                   const float* __restrict__ dis,
                                                   __bf16* __restrict__ Yb, int N) {
    int lane = threadIdx.x & 63, wave = threadIdx.x >> 6;
    int quad = lane >> 4, m = lane & 15;
    int r0 = blockIdx.x * 128 + wave * 32;

    f32x4 acc[2][8];
#pragma unroll
    for (int rt = 0; rt < 2; ++rt)
#pragma unroll
        for (int c = 0; c < 8; ++c) acc[rt][c] = (f32x4)0.0f;

    int ra = r0 + m;      if (ra >= N) ra = N - 1;
    int rb = r0 + 16 + m; if (rb >= N) rb = N - 1;
    const float* pxa = &X[(size_t)ra * F + quad * 8];
    const float* pxb = &X[(size_t)rb * F + quad * 8];

    float4 a0 = *(const float4*)pxa, a1 = *(const float4*)(pxa + 4);
    float4 a2 = *(const float4*)pxb, a3 = *(const float4*)(pxb + 4);

#pragma unroll 1
    for (int t = 0; t < 4; ++t) {
        const __bf16* bp = Bswz + (size_t)t * 4096 + lane * 8;
        bf16x8 B[8];
#pragma unroll
        for (int c = 0; c < 8; ++c) B[c] = *(const bf16x8*)(bp + c * 512);

        float fa[8] = {a0.x, a0.y, a0.z, a0.w, a1.x, a1.y, a1.z, a1.w};
        float fb[8] = {a2.x, a2.y, a2.z, a2.w, a3.x, a3.y, a3.z, a3.w};
        bf16x8 ah0, al0, ah1, al1;
#pragma unroll
        for (int j = 0; j < 8; ++j) {
            __bf16 h0 = (__bf16)fa[j]; ah0[j] = h0; al0[j] = (__bf16)(fa[j] - (float)h0);
            __bf16 h1 = (__bf16)fb[j]; ah1[j] = h1; al1[j] = (__bf16)(fb[j] - (float)h1);
        }
        if (t < 3) {
            a0 = *(const float4*)(pxa + (t + 1) * 32);
            a1 = *(const float4*)(pxa + (t + 1) * 32 + 4);
            a2 = *(const float4*)(pxb + (t + 1) * 32);
            a3 = *(const float4*)(pxb + (t + 1) * 32 + 4);
        }
#pragma unroll
        for (int c = 0; c < 8; ++c) {
            acc[0][c] = __builtin_amdgcn_mfma_f32_16x16x32_bf16(ah0, B[c], acc[0][c], 0, 0, 0);
            acc[0][c] = __builtin_amdgcn_mfma_f32_16x16x32_bf16(al0, B[c], acc[0][c], 0, 0, 0);
            acc[1][c] = __builtin_amdgcn_mfma_f32_16x16x32_bf16(ah1, B[c], acc[1][c], 0, 0, 0);
            acc[1][c] = __builtin_amdgcn_mfma_f32_16x16x32_bf16(al1, B[c], acc[1][c], 0, 0, 0);
        }
    }

#pragma unroll
    for (int rt = 0; rt < 2; ++rt) {
        int rbase = r0 + rt * 16 + quad * 4;
#pragma unroll
        for (int r = 0; r < 4; ++r) {
            int row = rbase + r;
            if (row < N) {
                float dr = dis[row];
#pragma unroll
                for (int c = 0; c < 8; ++c)
                    Yb[(size_t)row * F + c * 16 + m] = (__bf16)(acc[rt][c][r] * dr);
            }
        }
    }
}

// ---------------- layer-1 aggregation fused with zt = dis * (relu(b1 + dis*sum) . w2l) ------
// 8 lanes/node (each lane: 2x bf16x8 = 32B of the 256B row) -> 8 independent node chains/wave.
__global__ __launch_bounds__(256) void k_agg_z(const __bf16* __restrict__ hWb, const float* __restrict__ dis,
                                               const int* __restrict__ rowptr, const int* __restrict__ srcs,
                                               const float* __restrict__ bias, const float* __restrict__ w2l,
                                               float* __restrict__ zt, int N) {
    int node = blockIdx.x * 32 + (threadIdx.x >> 3);
    if (node >= N) return;
    int lane = threadIdx.x & 7;                   // 8 lanes/node, 16 elems/lane
    float di = dis[node];
    float s[16];
    {
        const __bf16* pr = &hWb[(size_t)node * F + lane * 16];
        bf16x8 v0 = *(const bf16x8*)pr;
        bf16x8 v1 = *(const bf16x8*)(pr + 8);
#pragma unroll
        for (int j = 0; j < 8; ++j) { s[j] = (float)v0[j]; s[8 + j] = (float)v1[j]; }
    }
    int e0 = rowptr[node], e1 = rowptr[node + 1];
    int e = e0;
    for (; e + 4 <= e1; e += 4) {
        int i0 = srcs[e], i1 = srcs[e + 1], i2 = srcs[e + 2], i3 = srcs[e + 3];
        const __bf16* p0 = &hWb[(size_t)i0 * F + lane * 16];
        const __bf16* p1 = &hWb[(size_t)i1 * F + lane * 16];
        const __bf16* p2 = &hWb[(size_t)i2 * F + lane * 16];
        const __bf16* p3 = &hWb[(size_t)i3 * F + lane * 16];
        bf16x8 a0 = *(const bf16x8*)p0, b0 = *(const bf16x8*)(p0 + 8);
        bf16x8 a1 = *(const bf16x8*)p1, b1 = *(const bf16x8*)(p1 + 8);
        bf16x8 a2 = *(const bf16x8*)p2, b2 = *(const bf16x8*)(p2 + 8);
        bf16x8 a3 = *(const bf16x8*)p3, b3 = *(const bf16x8*)(p3 + 8);
#pragma unroll
        for (int j = 0; j < 8; ++j) {
            s[j]     += (float)a0[j] + (float)a1[j] + (float)a2[j] + (float)a3[j];
            s[8 + j] += (float)b0[j] + (float)b1[j] + (float)b2[j] + (float)b3[j];
        }
    }
    for (; e < e1; ++e) {
        const __bf16* pr = &hWb[(size_t)srcs[e] * F + lane * 16];
        bf16x8 v0 = *(const bf16x8*)pr;
        bf16x8 v1 = *(const bf16x8*)(pr + 8);
#pragma unroll
        for (int j = 0; j < 8; ++j) { s[j] += (float)v0[j]; s[8 + j] += (float)v1[j]; }
    }
    float p = 0.0f;
#pragma unroll
    for (int q = 0; q < 4; ++q) {
        float4 bb = *(const float4*)&bias[lane * 16 + q * 4];
        float4 ww = *(const float4*)&w2l[lane * 16 + q * 4];
        p += fmaxf(fmaf(di, s[q * 4 + 0], bb.x), 0.0f) * ww.x;
        p += fmaxf(fmaf(di, s[q * 4 + 1], bb.y), 0.0f) * ww.y;
        p += fmaxf(fmaf(di, s[q * 4 + 2], bb.z), 0.0f) * ww.z;
        p += fmaxf(fmaf(di, s[q * 4 + 3], bb.w), 0.0f) * ww.w;
    }
#pragma unroll
    for (int d = 1; d < 8; d <<= 1) p += __shfl_xor(p, d);
    if (lane == 0) zt[node] = di * p;
}

// ---------------- layer-2 scalar aggregation + mean-pool ----------------
__global__ __launch_bounds__(256) void k_pool_z(const float* __restrict__ zt, const float* __restrict__ dis,
                                                const int* __restrict__ rowptr, const int* __restrict__ srcs,
                                                const int* __restrict__ batch,
                                                float* __restrict__ gacc, int N) {
    int n = blockIdx.x * 256 + threadIdx.x;
    float y = 0.0f;
    int b = -1;
    if (n < N) {
        float s = zt[n];
        int e0 = rowptr[n], e1 = rowptr[n + 1];
        int e = e0;
        for (; e + 4 <= e1; e += 4) {
            int s0 = srcs[e], s1 = srcs[e + 1], s2 = srcs[e + 2], s3 = srcs[e + 3];
            s += zt[s0] + zt[s1] + zt[s2] + zt[s3];
        }
        for (; e < e1; ++e) s += zt[srcs[e]];
        y = dis[n] * s;
        b = batch[n];
    }
    int bfirst = __shfl(b, 0), blast = __shfl(b, 63);
    if (bfirst == blast && bfirst >= 0) {
#pragma unroll
        for (int d = 1; d < 64; d <<= 1) y += __shfl_xor(y, d);
        if ((threadIdx.x & 63) == 0) unsafeAtomicAdd(&gacc[bfirst], y);
    } else if (n < N) {
        unsafeAtomicAdd(&gacc[b], y);
    }
}

__global__ __launch_bounds__(256) void k_final(const float* __restrict__ gacc, const float* __restrict__ cnt,
                                               const float* __restrict__ cconst, float* __restrict__ out, int G) {
    int g = blockIdx.x * 256 + threadIdx.x;
    if (g < G) out[g] = gacc[g] / fmaxf(cnt[g], 1.0f) + cconst[0];
}

// ---------------- launch ----------------

extern "C" void kernel_launch(void* const* d_in, const int* in_sizes, int n_in,
                              void* d_out, int out_size, void* d_ws, size_t ws_size,
                              hipStream_t stream) {
    const float* x    = (const float*)d_in[0];
    const int*   ei   = (const int*)d_in[1];
    const int*   batch= (const int*)d_in[2];
    const float* W1   = (const float*)d_in[3];
    const float* b1   = (const float*)d_in[4];
    const float* W2   = (const float*)d_in[5];
    const float* b2   = (const float*)d_in[6];
    const float* Wlin = (const float*)d_in[7];
    const float* blin = (const float*)d_in[8];
    float* out = (float*)d_out;

    const int N = in_sizes[2];          // 100000
    const int E = in_sizes[1] / 2;      // 600000
    const int G = out_size;             // 512
    const int* src = ei;
    const int* dst = ei + E;

    char* p = (char*)d_ws;
    auto take = [&](size_t bytes) { char* q = p; p += (bytes + 255) & ~(size_t)255; return q; };
    __bf16* hWb    = (__bf16*)take((size_t)N * F * 2);  // bf16( dis * (x @ W1) )
    float*  ztbuf  = (float*)take((size_t)N * 4);
    float*  deg    = (float*)take((size_t)N * 4);
    float*  dis    = (float*)take((size_t)N * 4);
    int*    rowptr = (int*)  take((size_t)(N + 1) * 4);
    int*    cursor = (int*)  take((size_t)N * 4);
    int*    srcs   = (int*)  take((size_t)E * 4);
    int*    bsum   = (int*)  take(4096);
    float*  cnt    = (float*)take((size_t)G * 4);
    float*  gacc   = (float*)take((size_t)G * 4);
    float*  w2l    = (float*)take((size_t)F * 4);
    float*  cconst = (float*)take(256);
    __bf16* Bswz   = (__bf16*)take((size_t)F * F * 2);

    const int nbN = (N + 255) / 256;
    const int nbE = (E + 255) / 256;
    const int nbS = (N + 1023) / 1024;

    k_init <<<nbN, 256, 0, stream>>>(deg, gacc, N, G);
    k_count<<<nbE, 256, 0, stream>>>(dst, deg, E);
    k_prep <<<65 + (G + 255) / 256, 256, 0, stream>>>(W1, W2, Wlin, b2, blin, batch,
                                                      Bswz, w2l, cconst, cnt, N, G);
    k_scan1<<<nbS, 256, 0, stream>>>(deg, rowptr, bsum, dis, N);
    k_scan3<<<nbN, 256, 0, stream>>>(rowptr, bsum, cursor, N, E);
    k_fill <<<nbE, 256, 0, stream>>>(src, dst, cursor, srcs, E);

    k_gemm_mfma<<<(N + 127) / 128, 256, 0, stream>>>(x, Bswz, dis, hWb, N);
    k_agg_z<<<(N + 31) / 32, 256, 0, stream>>>(hWb, dis, rowptr, srcs, b1, w2l, ztbuf, N);
    k_pool_z<<<nbN, 256, 0, stream>>>(ztbuf, dis, rowptr, srcs, batch, gacc, N);
    k_final<<<(G + 255) / 256, 256, 0, stream>>>(gacc, cnt, cconst, out, G);
}

// Round 8
// 221.044 us; speedup vs baseline: 1.5575x; 1.1776x over previous
//
#include <hip/hip_runtime.h>

#define F 128

typedef __bf16 bf16x8 __attribute__((ext_vector_type(8)));
typedef float f32x4 __attribute__((ext_vector_type(4)));

// ---------------- fused prep ----------------
// blocks 0..63: W1 swizzle->bf16 fragments; block 64: w2l/cconst + zero histg;
// blocks 65..65+bG-1: gstart via binary search; rest: deg = 1 init.
__global__ __launch_bounds__(256) void k_prep(const float* __restrict__ W1, const float* __restrict__ W2,
                                              const float* __restrict__ Wlin, const float* __restrict__ b2,
                                              const float* __restrict__ blin, const int* __restrict__ batch,
                                              __bf16* __restrict__ Bswz, float* __restrict__ w2l,
                                              float* __restrict__ cconst, int* __restrict__ gstart,
                                              int* __restrict__ histg, float* __restrict__ deg,
                                              int N, int G, int bG) {
    int bid = blockIdx.x;
    int tid = threadIdx.x;
    if (bid < 64) {
        // Bswz[((t*8+c)*64+lane)*8+j] = W1[t*32+(lane>>4)*8+j][c*16+(lane&15)]
        int o = bid * 256 + tid;
        int j = o & 7, lane = (o >> 3) & 63, tc = o >> 9;
        int t = tc >> 3, c = tc & 7;
        int k = t * 32 + (lane >> 4) * 8 + j;
        int n = c * 16 + (lane & 15);
        Bswz[o] = (__bf16)W1[k * F + n];
    } else if (bid == 64) {
        __shared__ float sh[F];
        if (tid < F) {
            float s = 0.0f;
            for (int j = 0; j < F; j += 4) {
                float4 w = *(const float4*)&W2[tid * F + j];
                float4 l = *(const float4*)&Wlin[j];
                s += w.x * l.x + w.y * l.y + w.z * l.z + w.w * l.w;
            }
            w2l[tid] = s;
            sh[tid] = b2[tid] * Wlin[tid];
        } else if (tid < F + 64) {
            histg[tid - F] = 0;
        }
        __syncthreads();
        if (tid == 0) {
            float c = blin[0];
            for (int j = 0; j < F; ++j) c += sh[j];
            *cconst = c;
        }
    } else if (bid < 65 + bG) {
        int g = (bid - 65) * 256 + tid;
        if (g < G) {
            int lo = 0, hi = N;
            while (lo < hi) { int mid = (lo + hi) >> 1; if (batch[mid] < g) lo = mid + 1; else hi = mid; }
            gstart[g] = lo;
            if (g == 0) gstart[G] = N;
        }
    } else {
        int i = (bid - 65 - bG) * 256 + tid;
        if (i < N) deg[i] = 1.0f;           // self-loop
    }
}

// degree count: random-address atomics, low contention
__global__ __launch_bounds__(256) void k_count(const int* __restrict__ dst, float* deg, int E) {
    int i = blockIdx.x * 256 + threadIdx.x;
    if (i < E) unsafeAtomicAdd(&deg[dst[i]], 1.0f);
}

// exclusive scan of indeg (=deg-1), 1024 elems/block; dis = rsqrt(deg); + degree histogram
__global__ __launch_bounds__(256) void k_scan1(const float* __restrict__ deg, int* __restrict__ pref,
                                               int* __restrict__ bsum, float* __restrict__ dis,
                                               int* __restrict__ histg, int N) {
    int t = threadIdx.x;
    __shared__ int lh[64];
    __shared__ int wtot[4];
    if (t < 64) lh[t] = 0;
    int base = blockIdx.x * 1024 + t * 4;
    int v[4]; int s = 0;
#pragma unroll
    for (int j = 0; j < 4; ++j) {
        int idx = base + j;
        float dv = (idx < N) ? deg[idx] : 1.0f;
        if (idx < N) dis[idx] = rsqrtf(dv);
        v[j] = (idx < N) ? ((int)dv - 1) : 0; s += v[j];
    }
    int lane = t & 63, w = t >> 6;
    int inc = s;
#pragma unroll
    for (int d = 1; d < 64; d <<= 1) { int o = __shfl_up(inc, d); if (lane >= d) inc += o; }
    if (lane == 63) wtot[w] = inc;
    __syncthreads();                          // covers lh init + wtot
#pragma unroll
    for (int j = 0; j < 4; ++j)
        if (base + j < N) atomicAdd(&lh[min(v[j], 63)], 1);
    int woff = 0;
#pragma unroll
    for (int i = 0; i < 4; ++i) if (i < w) woff += wtot[i];
    int run = woff + inc - s;
#pragma unroll
    for (int j = 0; j < 4; ++j) { int idx = base + j; if (idx < N) pref[idx] = run; run += v[j]; }
    if (t == 255) bsum[blockIdx.x] = woff + inc;
    __syncthreads();
    if (t < 64 && lh[t] > 0) atomicAdd(&histg[t], lh[t]);
}

// add block offsets (reduce bsum[0..chunk) in-block); block 0 also scans the 64-bin histogram
__global__ __launch_bounds__(256) void k_scan3(int* __restrict__ pref, const int* __restrict__ bsum,
                                               int* __restrict__ cursor, const int* __restrict__ histg,
                                               int* __restrict__ bcur, int N, int E) {
    int t = threadIdx.x;
    int chunk = blockIdx.x >> 2;
    int partial = 0;
    for (int i = t; i < chunk; i += 256) partial += bsum[i];
    int lane = t & 63, w = t >> 6;
#pragma unroll
    for (int d = 1; d < 64; d <<= 1) partial += __shfl_xor(partial, d);
    __shared__ int ws4[4];
    if (lane == 0) ws4[w] = partial;
    __syncthreads();
    int off = ws4[0] + ws4[1] + ws4[2] + ws4[3];
    int i = blockIdx.x * 256 + t;
    if (i < N) {
        int v = pref[i] + off;
        pref[i] = v;
        cursor[i] = v;
    }
    if (i == 0) pref[N] = E;
    if (blockIdx.x == 0 && t < 64) {          // exclusive scan of degree histogram -> bucket cursors
        int h = histg[t];
        int inc2 = h;
#pragma unroll
        for (int d = 1; d < 64; d <<= 1) { int o = __shfl_up(inc2, d); if (t >= d) inc2 += o; }
        bcur[t] = inc2 - h;
    }
}

// CSR fill (edge-parallel blocks) + degree-sorted perm scatter (node-parallel blocks)
__global__ __launch_bounds__(256) void k_fill(const int* __restrict__ src, const int* __restrict__ dst,
                                              const float* __restrict__ deg, int* __restrict__ cursor,
                                              int* __restrict__ srcs, int* __restrict__ bcur,
                                              int* __restrict__ perm, int E, int N, int nbN) {
    int bid = blockIdx.x, tid = threadIdx.x;
    if (bid < nbN) {
        __shared__ int lcnt[64], lbase[64];
        if (tid < 64) lcnt[tid] = 0;
        __syncthreads();
        int n = bid * 256 + tid;
        int b = 0, r = 0;
        if (n < N) {
            b = min((int)deg[n] - 1, 63);
            r = atomicAdd(&lcnt[b], 1);
        }
        __syncthreads();
        if (tid < 64 && lcnt[tid] > 0) lbase[tid] = atomicAdd(&bcur[tid], lcnt[tid]);
        __syncthreads();
        if (n < N) perm[lbase[b] + r] = n;
    } else {
        int e = (bid - nbN) * 256 + tid;
        if (e < E) {
            int s = src[e], d = dst[e];
            int slot = atomicAdd(&cursor[d], 1);
            srcs[slot] = s;
        }
    }
}

// ---------------- MFMA GEMM: Yb[n] = bf16( dis[n] * (X @ W)[n] ) ----------------
__global__ __launch_bounds__(256) void k_gemm_mfma(const float* __restrict__ X,
                                                   const __bf16* __restrict__ Bswz,
                                                   const float* __restrict__ dis,
                                                   __bf16* __restrict__ Yb, int N) {
    int lane = threadIdx.x & 63, wave = threadIdx.x >> 6;
    int quad = lane >> 4, m = lane & 15;
    int r0 = blockIdx.x * 128 + wave * 32;

    f32x4 acc[2][8];
#pragma unroll
    for (int rt = 0; rt < 2; ++rt)
#pragma unroll
        for (int c = 0; c < 8; ++c) acc[rt][c] = (f32x4)0.0f;

    int ra = r0 + m;      if (ra >= N) ra = N - 1;
    int rb = r0 + 16 + m; if (rb >= N) rb = N - 1;
    const float* pxa = &X[(size_t)ra * F + quad * 8];
    const float* pxb = &X[(size_t)rb * F + quad * 8];

    float4 a0 = *(const float4*)pxa, a1 = *(const float4*)(pxa + 4);
    float4 a2 = *(const float4*)pxb, a3 = *(const float4*)(pxb + 4);

#pragma unroll 1
    for (int t = 0; t < 4; ++t) {
        const __bf16* bp = Bswz + (size_t)t * 4096 + lane * 8;
        bf16x8 B[8];
#pragma unroll
        for (int c = 0; c < 8; ++c) B[c] = *(const bf16x8*)(bp + c * 512);

        float fa[8] = {a0.x, a0.y, a0.z, a0.w, a1.x, a1.y, a1.z, a1.w};
        float fb[8] = {a2.x, a2.y, a2.z, a2.w, a3.x, a3.y, a3.z, a3.w};
        bf16x8 ah0, al0, ah1, al1;
#pragma unroll
        for (int j = 0; j < 8; ++j) {
            __bf16 h0 = (__bf16)fa[j]; ah0[j] = h0; al0[j] = (__bf16)(fa[j] - (float)h0);
            __bf16 h1 = (__bf16)fb[j]; ah1[j] = h1; al1[j] = (__bf16)(fb[j] - (float)h1);
        }
        if (t < 3) {
            a0 = *(const float4*)(pxa + (t + 1) * 32);
            a1 = *(const float4*)(pxa + (t + 1) * 32 + 4);
            a2 = *(const float4*)(pxb + (t + 1) * 32);
            a3 = *(const float4*)(pxb + (t + 1) * 32 + 4);
        }
#pragma unroll
        for (int c = 0; c < 8; ++c) {
            acc[0][c] = __builtin_amdgcn_mfma_f32_16x16x32_bf16(ah0, B[c], acc[0][c], 0, 0, 0);
            acc[0][c] = __builtin_amdgcn_mfma_f32_16x16x32_bf16(al0, B[c], acc[0][c], 0, 0, 0);
            acc[1][c] = __builtin_amdgcn_mfma_f32_16x16x32_bf16(ah1, B[c], acc[1][c], 0, 0, 0);
            acc[1][c] = __builtin_amdgcn_mfma_f32_16x16x32_bf16(al1, B[c], acc[1][c], 0, 0, 0);
        }
    }

#pragma unroll
    for (int rt = 0; rt < 2; ++rt) {
        int rbase = r0 + rt * 16 + quad * 4;
#pragma unroll
        for (int r = 0; r < 4; ++r) {
            int row = rbase + r;
            if (row < N) {
                float dr = dis[row];
#pragma unroll
                for (int c = 0; c < 8; ++c)
                    Yb[(size_t)row * F + c * 16 + m] = (__bf16)(acc[rt][c][r] * dr);
            }
        }
    }
}

// ---------------- layer-1 aggregation + zt = dis*(relu(b1+dis*sum).w2l), degree-sorted ------
// 8 lanes/node; nodes processed in perm (degree) order -> no wave divergence in edge loop.
__global__ __launch_bounds__(256) void k_agg_z(const __bf16* __restrict__ hWb, const float* __restrict__ dis,
                                               const int* __restrict__ rowptr, const int* __restrict__ srcs,
                                               const int* __restrict__ perm,
                                               const float* __restrict__ bias, const float* __restrict__ w2l,
                                               float* __restrict__ zt, int N) {
    int idx = blockIdx.x * 32 + (threadIdx.x >> 3);
    if (idx >= N) return;
    int node = perm[idx];
    int lane = threadIdx.x & 7;                   // 8 lanes/node, 16 elems/lane
    float di = dis[node];
    float s[16];
    {
        const __bf16* pr = &hWb[(size_t)node * F + lane * 16];
        bf16x8 v0 = *(const bf16x8*)pr;
        bf16x8 v1 = *(const bf16x8*)(pr + 8);
#pragma unroll
        for (int j = 0; j < 8; ++j) { s[j] = (float)v0[j]; s[8 + j] = (float)v1[j]; }
    }
    int e0 = rowptr[node], e1 = rowptr[node + 1];
    int e = e0;
    for (; e + 4 <= e1; e += 4) {
        int i0 = srcs[e], i1 = srcs[e + 1], i2 = srcs[e + 2], i3 = srcs[e + 3];
        const __bf16* p0 = &hWb[(size_t)i0 * F + lane * 16];
        const __bf16* p1 = &hWb[(size_t)i1 * F + lane * 16];
        const __bf16* p2 = &hWb[(size_t)i2 * F + lane * 16];
        const __bf16* p3 = &hWb[(size_t)i3 * F + lane * 16];
        bf16x8 a0 = *(const bf16x8*)p0, b0 = *(const bf16x8*)(p0 + 8);
        bf16x8 a1 = *(const bf16x8*)p1, b1 = *(const bf16x8*)(p1 + 8);
        bf16x8 a2 = *(const bf16x8*)p2, b2 = *(const bf16x8*)(p2 + 8);
        bf16x8 a3 = *(const bf16x8*)p3, b3 = *(const bf16x8*)(p3 + 8);
#pragma unroll
        for (int j = 0; j < 8; ++j) {
            s[j]     += (float)a0[j] + (float)a1[j] + (float)a2[j] + (float)a3[j];
            s[8 + j] += (float)b0[j] + (float)b1[j] + (float)b2[j] + (float)b3[j];
        }
    }
    for (; e < e1; ++e) {
        const __bf16* pr = &hWb[(size_t)srcs[e] * F + lane * 16];
        bf16x8 v0 = *(const bf16x8*)pr;
        bf16x8 v1 = *(const bf16x8*)(pr + 8);
#pragma unroll
        for (int j = 0; j < 8; ++j) { s[j] += (float)v0[j]; s[8 + j] += (float)v1[j]; }
    }
    float p = 0.0f;
#pragma unroll
    for (int q = 0; q < 4; ++q) {
        float4 bb = *(const float4*)&bias[lane * 16 + q * 4];
        float4 ww = *(const float4*)&w2l[lane * 16 + q * 4];
        p += fmaxf(fmaf(di, s[q * 4 + 0], bb.x), 0.0f) * ww.x;
        p += fmaxf(fmaf(di, s[q * 4 + 1], bb.y), 0.0f) * ww.y;
        p += fmaxf(fmaf(di, s[q * 4 + 2], bb.z), 0.0f) * ww.z;
        p += fmaxf(fmaf(di, s[q * 4 + 3], bb.w), 0.0f) * ww.w;
    }
#pragma unroll
    for (int d = 1; d < 8; d <<= 1) p += __shfl_xor(p, d);
    if (lane == 0) zt[node] = di * p;
}

// ---------------- layer-2 aggregation + mean-pool: one block per graph, no atomics ----------
__global__ __launch_bounds__(256) void k_pool(const float* __restrict__ zt, const float* __restrict__ dis,
                                              const int* __restrict__ rowptr, const int* __restrict__ srcs,
                                              const int* __restrict__ gstart, const float* __restrict__ cconst,
                                              const float* __restrict__ blin, float* __restrict__ out, int G) {
    int g = blockIdx.x;
    int g0 = gstart[g], g1 = gstart[g + 1];
    float acc = 0.0f;
    for (int n = g0 + threadIdx.x; n < g1; n += 256) {
        float s = zt[n];
        int e0 = rowptr[n], e1 = rowptr[n + 1];
        int e = e0;
        for (; e + 4 <= e1; e += 4) {
            s += zt[srcs[e]] + zt[srcs[e + 1]] + zt[srcs[e + 2]] + zt[srcs[e + 3]];
        }
        for (; e < e1; ++e) s += zt[srcs[e]];
        acc += dis[n] * s;
    }
#pragma unroll
    for (int d = 1; d < 64; d <<= 1) acc += __shfl_xor(acc, d);
    __shared__ float ws4[4];
    if ((threadIdx.x & 63) == 0) ws4[threadIdx.x >> 6] = acc;
    __syncthreads();
    if (threadIdx.x == 0) {
        float sum = ws4[0] + ws4[1] + ws4[2] + ws4[3];
        int c = g1 - g0;
        out[g] = (c > 0) ? (sum / (float)c + cconst[0]) : blin[0];
    }
}

// ---------------- launch ----------------

extern "C" void kernel_launch(void* const* d_in, const int* in_sizes, int n_in,
                              void* d_out, int out_size, void* d_ws, size_t ws_size,
                              hipStream_t stream) {
    const float* x    = (const float*)d_in[0];
    const int*   ei   = (const int*)d_in[1];
    const int*   batch= (const int*)d_in[2];
    const float* W1   = (const float*)d_in[3];
    const float* b1   = (const float*)d_in[4];
    const float* W2   = (const float*)d_in[5];
    const float* b2   = (const float*)d_in[6];
    const float* Wlin = (const float*)d_in[7];
    const float* blin = (const float*)d_in[8];
    float* out = (float*)d_out;

    const int N = in_sizes[2];          // 100000
    const int E = in_sizes[1] / 2;      // 600000
    const int G = out_size;             // 512
    const int* src = ei;
    const int* dst = ei + E;

    char* p = (char*)d_ws;
    auto take = [&](size_t bytes) { char* q = p; p += (bytes + 255) & ~(size_t)255; return q; };
    __bf16* hWb    = (__bf16*)take((size_t)N * F * 2);  // bf16( dis * (x @ W1) )
    float*  ztbuf  = (float*)take((size_t)N * 4);
    float*  deg    = (float*)take((size_t)N * 4);
    float*  dis    = (float*)take((size_t)N * 4);
    int*    rowptr = (int*)  take((size_t)(N + 1) * 4);
    int*    cursor = (int*)  take((size_t)N * 4);
    int*    srcs   = (int*)  take((size_t)E * 4);
    int*    perm   = (int*)  take((size_t)N * 4);
    int*    bsum   = (int*)  take(4096);
    int*    histg  = (int*)  take(64 * 4);
    int*    bcur   = (int*)  take(64 * 4);
    int*    gstart = (int*)  take((size_t)(G + 1) * 4);
    float*  w2l    = (float*)take((size_t)F * 4);
    float*  cconst = (float*)take(256);
    __bf16* Bswz   = (__bf16*)take((size_t)F * F * 2);

    const int nbN = (N + 255) / 256;
    const int nbE = (E + 255) / 256;
    const int nbS = (N + 1023) / 1024;
    const int bG  = (G + 255) / 256;

    k_prep <<<65 + bG + nbN, 256, 0, stream>>>(W1, W2, Wlin, b2, blin, batch,
                                               Bswz, w2l, cconst, gstart, histg, deg, N, G, bG);
    k_count<<<nbE, 256, 0, stream>>>(dst, deg, E);
    k_scan1<<<nbS, 256, 0, stream>>>(deg, rowptr, bsum, dis, histg, N);
    k_scan3<<<nbN, 256, 0, stream>>>(rowptr, bsum, cursor, histg, bcur, N, E);
    k_fill <<<nbN + nbE, 256, 0, stream>>>(src, dst, deg, cursor, srcs, bcur, perm, E, N, nbN);

    k_gemm_mfma<<<(N + 127) / 128, 256, 0, stream>>>(x, Bswz, dis, hWb, N);
    k_agg_z<<<(N + 31) / 32, 256, 0, stream>>>(hWb, dis, rowptr, srcs, perm, b1, w2l, ztbuf, N);
    k_pool <<<G, 256, 0, stream>>>(ztbuf, dis, rowptr, srcs, gstart, cconst, blin, out, G);
}